// Round 1
// baseline (77.754 us; speedup 1.0000x reference)
//
#include <hip/hip_runtime.h>
#include <math.h>

// TDVP_V2: BATCH=16384 chains, N=64 sites, D=4, DIN=DOUT=2.
// v17: wave-uniform segment remap. Previous best v15 = 77.0-77.7 us JSON,
// of which ~42 us is the harness's 268 MB poison-fill (top-5 profile rows are
// all fillBufferAligned @ ~42 us; tdvp_kernel < 42 us => kernel ~35 us).
// Theory: kernel is LDS-pipe + latency bound at a hard 2 waves/SIMD
// (2048 waves total). ~192 ds_read_b128/thread (A: 64, B: 128) are pure
// BROADCASTS (all chains read the same site data). Remap so a wave = one
// segment x 64 chains => A/B addresses are wave-uniform => compiler emits
// s_load into SGPRs: LDS traffic for A/B vanishes, bq[8] (32 VGPR) vanishes,
// scan loops become divergence-free scalar loops (7 iters/wave vs 8),
// n==0/63 edge branches become scalar.
// Structure:
//   512 threads/block = 64 chains (bb=tid&63) x 8 segments (s=tid>>6,
//   readfirstlane'd => wave-uniform). 256 blocks = 1 block/CU, 8 waves/CU,
//   2 waves/SIMD (thread-count-capped, same as v15).
//   LDS 33.3 KB: single union buffer sU.
//     life 1: x staging / y staging  [64 chains][130]   (33.3 KB)
//     life 2: sP segment products    [8 t][16 e][64 bb] (32 KB)
//   Lifetimes disjoint (x fully consumed into regs before P written; scans
//   finish reading sP before epilogue writes y) — 2 extra barriers.
// Predicted: dur 77.7 -> ~64-70 us; kernel VALUBusy ~2x up; bank-conflict ~0;
// FETCH_SIZE +~6 MB (A/B per-block re-fetch, L2/K$-served).

#define EPS 1e-6f
#define RSQ(x) __builtin_amdgcn_rsqf((x) + 1e-30f)

__global__ __launch_bounds__(512, 2)
void tdvp_kernel(const float* __restrict__ x,
                 const float* __restrict__ A,
                 const float* __restrict__ Bw,
                 const float* __restrict__ scale,
                 float* __restrict__ y)
{
    // Union LDS: max(64*130, 8*16*64) = 8320 floats = 33.3 KB.
    __shared__ float sU[8320];

    const int tid = threadIdx.x;
    const int bb  = tid & 63;                                  // chain in block
    const int s   = __builtin_amdgcn_readfirstlane(tid >> 6);  // segment 0..7, wave-uniform

    // ---- stage x (fully coalesced float4) into union buffer --------------
    {
        const float4* xg = (const float4*)x + (size_t)blockIdx.x * 2048;
        #pragma unroll
        for (int it = 0; it < 4; ++it) {
            const int g = it * 512 + tid;
            const float4 v = xg[g];
            const int c = g >> 5, f = (g & 31) * 4;
            *(float2*)&sU[c * 130 + f]     = make_float2(v.x, v.y);
            *(float2*)&sU[c * 130 + f + 2] = make_float2(v.z, v.w);
        }
    }
    __syncthreads();

    // ---- my 8 sites from LDS, normalized --------------------------------
    const int n0 = s * 8;
    float xa[8], xc[8];
    #pragma unroll
    for (int k = 0; k < 8; ++k) {
        const float2 v = *(const float2*)&sU[bb * 130 + n0 * 2 + 2 * k];
        const float inr = RSQ(v.x * v.x + v.y * v.y);
        xa[k] = v.x * inr; xc[k] = v.y * inr;
    }
    __syncthreads();   // x consumed -> sU becomes sP

    // ---- build all 8 M matrices (A via wave-uniform s_loads) -------------
    float M[8][16];
    #pragma unroll
    for (int k = 0; k < 8; ++k) {
        const float* Ak = A + (size_t)(n0 + k) * 32;
        #pragma unroll
        for (int e = 0; e < 16; ++e)
            M[k][e] = fmaf(xc[k], Ak[2 * e + 1], xa[k] * Ak[2 * e]);
    }

    // ---- phase 1: segment product P = M[0]..M[7] (normalized) -> sP ------
    {
        float P[16];
        #pragma unroll
        for (int e = 0; e < 16; ++e) P[e] = M[0][e];
        #pragma unroll
        for (int k = 1; k < 8; ++k) {
            float Pn[16];
            #pragma unroll
            for (int i = 0; i < 4; ++i) {
                #pragma unroll
                for (int j = 0; j < 4; ++j) {
                    float acc = P[i*4] * M[k][j];
                    acc = fmaf(P[i*4+1], M[k][4+j],  acc);
                    acc = fmaf(P[i*4+2], M[k][8+j],  acc);
                    acc = fmaf(P[i*4+3], M[k][12+j], acc);
                    Pn[i*4+j] = acc;
                }
            }
            #pragma unroll
            for (int e = 0; e < 16; ++e) P[e] = Pn[e];
        }
        float ss = 0.f;
        #pragma unroll
        for (int e = 0; e < 16; ++e) ss = fmaf(P[e], P[e], ss);
        const float rn = RSQ(ss);
        #pragma unroll
        for (int e = 0; e < 16; ++e)
            sU[s * 1024 + e * 64 + bb] = P[e] * rn;
    }
    __syncthreads();

    // ---- phase 2: prefix / suffix vector scans (scalar loop bounds) ------
    float v0 = 1.f, v1 = 0.f, v2 = 0.f, v3 = 0.f;
    #pragma unroll 1
    for (int t = 0; t < s; ++t) {
        const float* pp = &sU[t * 1024 + bb];
        const float p0  = pp[0],      p1  = pp[64],     p2  = pp[128],    p3  = pp[192];
        const float p4  = pp[256],    p5  = pp[320],    p6  = pp[384],    p7  = pp[448];
        const float p8  = pp[512],    p9  = pp[576],    p10 = pp[640],    p11 = pp[704];
        const float p12 = pp[768],    p13 = pp[832],    p14 = pp[896],    p15 = pp[960];
        const float w0 = v0*p0 + v1*p4 + v2*p8  + v3*p12;
        const float w1 = v0*p1 + v1*p5 + v2*p9  + v3*p13;
        const float w2 = v0*p2 + v1*p6 + v2*p10 + v3*p14;
        const float w3 = v0*p3 + v1*p7 + v2*p11 + v3*p15;
        const float rn = RSQ(w0*w0 + w1*w1 + w2*w2 + w3*w3);
        v0 = w0*rn; v1 = w1*rn; v2 = w2*rn; v3 = w3*rn;
    }
    float u0 = 1.f, u1 = 0.f, u2 = 0.f, u3 = 0.f;
    #pragma unroll 1
    for (int t = 7; t > s; --t) {
        const float* pp = &sU[t * 1024 + bb];
        const float p0  = pp[0],      p1  = pp[64],     p2  = pp[128],    p3  = pp[192];
        const float p4  = pp[256],    p5  = pp[320],    p6  = pp[384],    p7  = pp[448];
        const float p8  = pp[512],    p9  = pp[576],    p10 = pp[640],    p11 = pp[704];
        const float p12 = pp[768],    p13 = pp[832],    p14 = pp[896],    p15 = pp[960];
        const float w0 = p0*u0  + p1*u1  + p2*u2  + p3*u3;
        const float w1 = p4*u0  + p5*u1  + p6*u2  + p7*u3;
        const float w2 = p8*u0  + p9*u1  + p10*u2 + p11*u3;
        const float w3 = p12*u0 + p13*u1 + p14*u2 + p15*u3;
        const float rn = RSQ(w0*w0 + w1*w1 + w2*w2 + w3*w3);
        u0 = w0*rn; u1 = w1*rn; u2 = w2*rn; u3 = w3*rn;
    }

    // ---- phase 3a: forward walk, vl per site (cached M) ------------------
    float vlA[8], vlB[8], vlC[8], vlD[8];
    {
        float a0 = v0, a1 = v1, a2 = v2, a3 = v3;
        #pragma unroll
        for (int k = 0; k < 8; ++k) {
            vlA[k] = a0; vlB[k] = a1; vlC[k] = a2; vlD[k] = a3;
            if (k == 7) break;
            const float t0 = a0*M[k][0] + a1*M[k][4] + a2*M[k][8]  + a3*M[k][12];
            const float t1 = a0*M[k][1] + a1*M[k][5] + a2*M[k][9]  + a3*M[k][13];
            const float t2 = a0*M[k][2] + a1*M[k][6] + a2*M[k][10] + a3*M[k][14];
            const float t3 = a0*M[k][3] + a1*M[k][7] + a2*M[k][11] + a3*M[k][15];
            a0 = t0; a1 = t1; a2 = t2; a3 = t3;
        }
    }
    __syncthreads();   // scans done reading sP -> sU becomes y staging

    // ---- phase 3b: backward walk + fused epilogue (B via s_loads) --------
    const float sc = scale[0];
    #pragma unroll
    for (int kk = 7; kk >= 0; --kk) {
        const int n = n0 + kk;

        const float arn = RSQ(u0*u0 + u1*u1 + u2*u2 + u3*u3);
        float aa0 = u0*arn, aa1 = u1*arn, aa2 = u2*arn, aa3 = u3*arn;
        if (n == 63) { aa0 = 1.f; aa1 = aa2 = aa3 = 0.f; }

        const float wn = RSQ(vlA[kk]*vlA[kk] + vlB[kk]*vlB[kk] +
                             vlC[kk]*vlC[kk] + vlD[kk]*vlD[kk]);
        float vv0 = vlA[kk]*wn, vv1 = vlB[kk]*wn, vv2 = vlC[kk]*wn, vv3 = vlD[kk]*wn;
        if (n == 0) { vv0 = 1.f; vv1 = vv2 = vv3 = 0.f; }

        const float vv[4] = {vv0, vv1, vv2, vv3};
        const float aa[4] = {aa0, aa1, aa2, aa3};
        const float* Bn = Bw + (size_t)n * 64;      // wave-uniform -> SGPR
        float H00 = 0.f, H01 = 0.f, H10 = 0.f, H11 = 0.f;
        #pragma unroll
        for (int i = 0; i < 4; ++i) {
            #pragma unroll
            for (int l = 0; l < 4; ++l) {
                const float c = vv[i] * aa[l];
                const int   q = (i * 4 + l) * 4;
                H00 = fmaf(c, Bn[q + 0], H00);
                H01 = fmaf(c, Bn[q + 1], H01);
                H10 = fmaf(c, Bn[q + 2], H10);
                H11 = fmaf(c, Bn[q + 3], H11);
            }
        }
        const float rh = sc * RSQ(H00*H00 + H01*H01 + H10*H10 + H11*H11);
        H00 *= rh; H01 *= rh; H10 *= rh; H11 *= rh;
        if (__builtin_isnan(H00)) H00 = 0.f;
        if (__builtin_isnan(H01)) H01 = 0.f;
        if (__builtin_isnan(H10)) H10 = 0.f;
        if (__builtin_isnan(H11)) H11 = 0.f;
        H00 = fmaxf(H00, 0.f); H01 = fmaxf(H01, 0.f);
        H10 = fmaxf(H10, 0.f); H11 = fmaxf(H11, 0.f);

        float2 yo;
        yo.x = fmaf(H01, xc[kk], H00 * xa[kk]);
        yo.y = fmaf(H11, xc[kk], H10 * xa[kk]);
        *(float2*)&sU[bb * 130 + 2 * n] = yo;

        if (kk > 0) {   // u <- M[kk].u  (raw suffix for site n-1)
            const float t0 = M[kk][0]*u0  + M[kk][1]*u1  + M[kk][2]*u2  + M[kk][3]*u3;
            const float t1 = M[kk][4]*u0  + M[kk][5]*u1  + M[kk][6]*u2  + M[kk][7]*u3;
            const float t2 = M[kk][8]*u0  + M[kk][9]*u1  + M[kk][10]*u2 + M[kk][11]*u3;
            const float t3 = M[kk][12]*u0 + M[kk][13]*u1 + M[kk][14]*u2 + M[kk][15]*u3;
            u0 = t0; u1 = t1; u2 = t2; u3 = t3;
        }
    }
    __syncthreads();

    // ---- y out: fully coalesced float4 stores ----------------------------
    {
        float4* yg = (float4*)y + (size_t)blockIdx.x * 2048;
        #pragma unroll
        for (int it = 0; it < 4; ++it) {
            const int g = it * 512 + tid;
            const int c = g >> 5, f = (g & 31) * 4;
            const float2 a = *(const float2*)&sU[c * 130 + f];
            const float2 b = *(const float2*)&sU[c * 130 + f + 2];
            yg[g] = make_float4(a.x, a.y, b.x, b.y);
        }
    }
}

extern "C" void kernel_launch(void* const* d_in, const int* in_sizes, int n_in,
                              void* d_out, int out_size, void* d_ws, size_t ws_size,
                              hipStream_t stream) {
    const float* x     = (const float*)d_in[0];
    const float* A     = (const float*)d_in[1];
    const float* B     = (const float*)d_in[2];
    const float* scale = (const float*)d_in[3];
    float* yp = (float*)d_out;
    const int batch  = in_sizes[0] / 128;    // 16384
    const int blocks = batch / 64;           // 256 blocks x 512 threads
    tdvp_kernel<<<blocks, 512, 0, stream>>>(x, A, B, scale, yp);
}

// Round 2
// 77.696 us; speedup vs baseline: 1.0007x; 1.0007x over previous
//
#include <hip/hip_runtime.h>
#include <math.h>

// TDVP_V2: BATCH=16384 chains, N=64 sites, D=4, DIN=DOUT=2.
// v18: occupancy attack. Evidence: v15 (A/B in LDS) and v17 (A/B wave-uniform
// global/scalar) both land at ~37 us kernel (77.7 JSON - 40.3 fill) =>
// operand routing is NOT the bottleneck. VALU issue floor ~4 us, LDS pipe
// ~5 us => SIMDs ~85% idle => latency-bound at 2 waves/SIMD (2048 waves,
// grid-capped by 16384 chains x 8 segments).
// Fix: 16 segments x 64 chains = 1024-thread blocks, 4096 waves = 4/SIMD.
// Launchability: a 1024-thread block needs 4 waves/SIMD resident, so VGPR
// must be <=128 (512-VGPR pool/SIMD). (This is why the old session's
// >256-thread blocks "never launched" at ~200+ VGPR.) So: NO M[..][16]
// register cache — M recomputed per use (P-build, fwd walk, bwd walk) from
// xa/xc + wave-uniform A loads (~320 extra FMA/thread, issue-cheap).
// __launch_bounds__(1024,4) enforces the cap.
// Scans: serial per-thread (15 iters total/wave, wave-uniform trip counts),
// sP packed as [t][epair][bb][2] so each iter is 8x ds_read_b64 with banks
// evenly 4-covered (~free) instead of 16x b32.
// LDS 64KB union sU: life1 x/y staging [64][130] (33KB), life2 sP
// [16][8][64][2] (64KB). Grid 256 blocks x 1024 threads, 1 block/CU.
// Predicted: dur 77.7 -> ~62-68 us (kernel 37 -> 22-28), occupancy ~2x,
// VGPR <= 128, absmax ~0.004 unchanged. If neutral => fixed floor, probe it.

#define EPS 1e-6f
#define RSQ(x) __builtin_amdgcn_rsqf((x) + 1e-30f)

// build M for site n (row-major l*4+r) from normalized x components
#define BUILD_M(Mk, Ak, xav, xcv)                                   \
    {                                                               \
        _Pragma("unroll")                                           \
        for (int e = 0; e < 16; ++e)                                \
            Mk[e] = fmaf((xcv), (Ak)[2*e+1], (xav) * (Ak)[2*e]);    \
    }

__global__ __launch_bounds__(1024, 4)
void tdvp_kernel(const float* __restrict__ x,
                 const float* __restrict__ A,
                 const float* __restrict__ Bw,
                 const float* __restrict__ scale,
                 float* __restrict__ y)
{
    // union: max(x/y staging 64*130=8320, sP 16*8*64*2=16384) = 64 KB
    __shared__ float sU[16384];

    const int tid = threadIdx.x;
    const int bb  = tid & 63;                                  // chain in block
    const int s   = __builtin_amdgcn_readfirstlane(tid >> 6);  // segment 0..15

    // ---- stage x (fully coalesced float4) --------------------------------
    {
        const float4* xg = (const float4*)x + (size_t)blockIdx.x * 2048;
        #pragma unroll
        for (int it = 0; it < 2; ++it) {
            const int g = it * 1024 + tid;
            const float4 v = xg[g];
            const int c = g >> 5, f = (g & 31) * 4;
            *(float2*)&sU[c * 130 + f]     = make_float2(v.x, v.y);
            *(float2*)&sU[c * 130 + f + 2] = make_float2(v.z, v.w);
        }
    }
    __syncthreads();

    // ---- my 4 sites, normalized -----------------------------------------
    const int n0 = s * 4;
    float xa[4], xc[4];
    #pragma unroll
    for (int k = 0; k < 4; ++k) {
        const float2 v = *(const float2*)&sU[bb * 130 + n0 * 2 + 2 * k];
        const float inr = RSQ(v.x * v.x + v.y * v.y);
        xa[k] = v.x * inr; xc[k] = v.y * inr;
    }
    __syncthreads();   // x consumed -> sU becomes sP

    // ---- phase 1: P = M0*M1*M2*M3 (normalized) -> sP ---------------------
    {
        float P[16];
        {
            const float* Ak = A + (size_t)n0 * 32;
            BUILD_M(P, Ak, xa[0], xc[0]);
        }
        #pragma unroll
        for (int k = 1; k < 4; ++k) {
            float Mk[16];
            const float* Ak = A + (size_t)(n0 + k) * 32;
            BUILD_M(Mk, Ak, xa[k], xc[k]);
            float Pn[16];
            #pragma unroll
            for (int i = 0; i < 4; ++i) {
                #pragma unroll
                for (int j = 0; j < 4; ++j) {
                    float acc = P[i*4] * Mk[j];
                    acc = fmaf(P[i*4+1], Mk[4+j],  acc);
                    acc = fmaf(P[i*4+2], Mk[8+j],  acc);
                    acc = fmaf(P[i*4+3], Mk[12+j], acc);
                    Pn[i*4+j] = acc;
                }
            }
            #pragma unroll
            for (int e = 0; e < 16; ++e) P[e] = Pn[e];
        }
        float ss = 0.f;
        #pragma unroll
        for (int e = 0; e < 16; ++e) ss = fmaf(P[e], P[e], ss);
        const float rn = RSQ(ss);
        #pragma unroll
        for (int ep = 0; ep < 8; ++ep)
            *(float2*)&sU[s * 1024 + ep * 128 + bb * 2] =
                make_float2(P[2*ep] * rn, P[2*ep+1] * rn);
    }
    __syncthreads();

    // ---- phase 2: prefix / suffix vector scans (wave-uniform trips) ------
    float v0 = 1.f, v1 = 0.f, v2 = 0.f, v3 = 0.f;
    #pragma unroll 1
    for (int t = 0; t < s; ++t) {
        const float* pp = &sU[t * 1024 + bb * 2];
        float p[16];
        #pragma unroll
        for (int ep = 0; ep < 8; ++ep) {
            const float2 q = *(const float2*)&pp[ep * 128];
            p[2*ep] = q.x; p[2*ep+1] = q.y;
        }
        const float w0 = v0*p[0] + v1*p[4] + v2*p[8]  + v3*p[12];
        const float w1 = v0*p[1] + v1*p[5] + v2*p[9]  + v3*p[13];
        const float w2 = v0*p[2] + v1*p[6] + v2*p[10] + v3*p[14];
        const float w3 = v0*p[3] + v1*p[7] + v2*p[11] + v3*p[15];
        const float rn = RSQ(w0*w0 + w1*w1 + w2*w2 + w3*w3);
        v0 = w0*rn; v1 = w1*rn; v2 = w2*rn; v3 = w3*rn;
    }
    float u0 = 1.f, u1 = 0.f, u2 = 0.f, u3 = 0.f;
    #pragma unroll 1
    for (int t = 15; t > s; --t) {
        const float* pp = &sU[t * 1024 + bb * 2];
        float p[16];
        #pragma unroll
        for (int ep = 0; ep < 8; ++ep) {
            const float2 q = *(const float2*)&pp[ep * 128];
            p[2*ep] = q.x; p[2*ep+1] = q.y;
        }
        const float w0 = p[0]*u0  + p[1]*u1  + p[2]*u2  + p[3]*u3;
        const float w1 = p[4]*u0  + p[5]*u1  + p[6]*u2  + p[7]*u3;
        const float w2 = p[8]*u0  + p[9]*u1  + p[10]*u2 + p[11]*u3;
        const float w3 = p[12]*u0 + p[13]*u1 + p[14]*u2 + p[15]*u3;
        const float rn = RSQ(w0*w0 + w1*w1 + w2*w2 + w3*w3);
        u0 = w0*rn; u1 = w1*rn; u2 = w2*rn; u3 = w3*rn;
    }

    // ---- phase 3a: forward walk, vl per site (M recomputed) --------------
    float vlA[4], vlB[4], vlC[4], vlD[4];
    {
        float a0 = v0, a1 = v1, a2 = v2, a3 = v3;
        #pragma unroll
        for (int k = 0; k < 4; ++k) {
            vlA[k] = a0; vlB[k] = a1; vlC[k] = a2; vlD[k] = a3;
            if (k == 3) break;
            float Mk[16];
            const float* Ak = A + (size_t)(n0 + k) * 32;
            BUILD_M(Mk, Ak, xa[k], xc[k]);
            const float t0 = a0*Mk[0] + a1*Mk[4] + a2*Mk[8]  + a3*Mk[12];
            const float t1 = a0*Mk[1] + a1*Mk[5] + a2*Mk[9]  + a3*Mk[13];
            const float t2 = a0*Mk[2] + a1*Mk[6] + a2*Mk[10] + a3*Mk[14];
            const float t3 = a0*Mk[3] + a1*Mk[7] + a2*Mk[11] + a3*Mk[15];
            a0 = t0; a1 = t1; a2 = t2; a3 = t3;
        }
    }
    __syncthreads();   // scans done reading sP -> sU becomes y staging

    // ---- phase 3b: backward walk + fused epilogue ------------------------
    const float sc = scale[0];
    #pragma unroll
    for (int kk = 3; kk >= 0; --kk) {
        const int n = n0 + kk;

        const float arn = RSQ(u0*u0 + u1*u1 + u2*u2 + u3*u3);
        float aa0 = u0*arn, aa1 = u1*arn, aa2 = u2*arn, aa3 = u3*arn;
        if (n == 63) { aa0 = 1.f; aa1 = aa2 = aa3 = 0.f; }

        const float wn = RSQ(vlA[kk]*vlA[kk] + vlB[kk]*vlB[kk] +
                             vlC[kk]*vlC[kk] + vlD[kk]*vlD[kk]);
        float vv0 = vlA[kk]*wn, vv1 = vlB[kk]*wn, vv2 = vlC[kk]*wn, vv3 = vlD[kk]*wn;
        if (n == 0) { vv0 = 1.f; vv1 = vv2 = vv3 = 0.f; }

        const float vv[4] = {vv0, vv1, vv2, vv3};
        const float aa[4] = {aa0, aa1, aa2, aa3};
        const float* Bn = Bw + (size_t)n * 64;      // wave-uniform
        float H00 = 0.f, H01 = 0.f, H10 = 0.f, H11 = 0.f;
        #pragma unroll
        for (int i = 0; i < 4; ++i) {
            #pragma unroll
            for (int l = 0; l < 4; ++l) {
                const float c = vv[i] * aa[l];
                const int   q = (i * 4 + l) * 4;
                H00 = fmaf(c, Bn[q + 0], H00);
                H01 = fmaf(c, Bn[q + 1], H01);
                H10 = fmaf(c, Bn[q + 2], H10);
                H11 = fmaf(c, Bn[q + 3], H11);
            }
        }
        const float rh = sc * RSQ(H00*H00 + H01*H01 + H10*H10 + H11*H11);
        H00 *= rh; H01 *= rh; H10 *= rh; H11 *= rh;
        if (__builtin_isnan(H00)) H00 = 0.f;
        if (__builtin_isnan(H01)) H01 = 0.f;
        if (__builtin_isnan(H10)) H10 = 0.f;
        if (__builtin_isnan(H11)) H11 = 0.f;
        H00 = fmaxf(H00, 0.f); H01 = fmaxf(H01, 0.f);
        H10 = fmaxf(H10, 0.f); H11 = fmaxf(H11, 0.f);

        float2 yo;
        yo.x = fmaf(H01, xc[kk], H00 * xa[kk]);
        yo.y = fmaf(H11, xc[kk], H10 * xa[kk]);
        *(float2*)&sU[bb * 130 + 2 * n] = yo;

        if (kk > 0) {   // u <- M[kk].u  (raw suffix for site n-1)
            float Mk[16];
            const float* Ak = A + (size_t)(n0 + kk) * 32;
            BUILD_M(Mk, Ak, xa[kk], xc[kk]);
            const float t0 = Mk[0]*u0  + Mk[1]*u1  + Mk[2]*u2  + Mk[3]*u3;
            const float t1 = Mk[4]*u0  + Mk[5]*u1  + Mk[6]*u2  + Mk[7]*u3;
            const float t2 = Mk[8]*u0  + Mk[9]*u1  + Mk[10]*u2 + Mk[11]*u3;
            const float t3 = Mk[12]*u0 + Mk[13]*u1 + Mk[14]*u2 + Mk[15]*u3;
            u0 = t0; u1 = t1; u2 = t2; u3 = t3;
        }
    }
    __syncthreads();

    // ---- y out: fully coalesced float4 stores ----------------------------
    {
        float4* yg = (float4*)y + (size_t)blockIdx.x * 2048;
        #pragma unroll
        for (int it = 0; it < 2; ++it) {
            const int g = it * 1024 + tid;
            const int c = g >> 5, f = (g & 31) * 4;
            const float2 a = *(const float2*)&sU[c * 130 + f];
            const float2 b = *(const float2*)&sU[c * 130 + f + 2];
            yg[g] = make_float4(a.x, a.y, b.x, b.y);
        }
    }
}

extern "C" void kernel_launch(void* const* d_in, const int* in_sizes, int n_in,
                              void* d_out, int out_size, void* d_ws, size_t ws_size,
                              hipStream_t stream) {
    const float* x     = (const float*)d_in[0];
    const float* A     = (const float*)d_in[1];
    const float* B     = (const float*)d_in[2];
    const float* scale = (const float*)d_in[3];
    float* yp = (float*)d_out;
    const int batch  = in_sizes[0] / 128;    // 16384
    const int blocks = batch / 64;           // 256 blocks x 1024 threads
    tdvp_kernel<<<blocks, 1024, 0, stream>>>(x, A, B, scale, yp);
}